// Round 1
// baseline (139.540 us; speedup 1.0000x reference)
//
#include <hip/hip_runtime.h>

// SparseFlowModel — two-kernel version.
// coords: [4, 2048, 3] int32 in [0,64). Outputs (concat flat, float32):
//   prior [4,2048,4096]  then  occ [4,2048,26]
//
// Hash x*100003+y*1009+z is injective over [-1,64]^3 -> neighbor matching is
// exact coord membership; out-of-range neighbors never match.
//
// K1 (occ_kernel): 64 blocks/batch, each rebuilds the batch's 64^3 occupancy
//   bitmap (32 KB LDS) and writes occ flags for 32 points. The first 6 occ
//   entries per point ARE the face-existence bits (FACE_OFFSETS == NB_OFF[0:6]),
//   so K1's output doubles as K2's input — no workspace handoff.
// K2 (prior_kernel): LDS-free pure-streaming kernel. 2048 blocks x 256 thr
//   (8 blocks/CU = 32 waves/CU, 100% occupancy), each handles 4 points:
//   reads 6 face floats from the occ region (L1 broadcast) and streams the
//   16 KB prior tile as coalesced float4 stores.
// Stream order guarantees K1 -> K2 visibility (kernel-boundary release/acquire).

#define B 4
#define N 2048
#define BM_WORDS 8192                       // 64^3 / 32
#define PRIOR_ELEMS (4ull * 2048ull * 4096ull)

#define K1_BPB 64                           // K1 blocks per batch
#define K1_PTS (N / K1_BPB)                 // 32 points per K1 block
#define PPB2 4                              // points per K2 block

static __device__ __constant__ int NB_OFF[26][3] = {
    {-1,0,0},{1,0,0},{0,-1,0},{0,1,0},{0,0,-1},{0,0,1},
    {-1,-1,0},{-1,1,0},{1,-1,0},{1,1,0},
    {-1,0,-1},{-1,0,1},{1,0,-1},{1,0,1},
    {0,-1,-1},{0,-1,1},{0,1,-1},{0,1,1},
    {-1,-1,-1},{-1,-1,1},{-1,1,-1},{-1,1,1},
    {1,-1,-1},{1,-1,1},{1,1,-1},{1,1,1}
};

__device__ __forceinline__ bool bm_test(const unsigned* bm, int x, int y, int z) {
    if (((x | y | z) & ~63) != 0) return false;   // negatives or >=64 -> absent
    unsigned idx = ((unsigned)x << 12) | ((unsigned)y << 6) | (unsigned)z;
    return (bm[idx >> 5] >> (idx & 31u)) & 1u;
}

// ---- K1: occupancy flags (and, implicitly, face-existence bits) ----
__global__ void __launch_bounds__(256, 4)
occ_kernel(const int* __restrict__ coords, float* __restrict__ out) {
    __shared__ unsigned bm[BM_WORDS];

    const int tid = threadIdx.x;
    const int blk = blockIdx.x;                 // 0..255
    const int b = blk / K1_BPB;
    const int p0 = (blk % K1_BPB) * K1_PTS;
    const int* cb = coords + b * N * 3;

    // zero bitmap (32 words/thread)
    for (int i = tid; i < BM_WORDS; i += 256) bm[i] = 0u;
    __syncthreads();

    // scatter all 2048 batch points (8/thread); coords are L2-resident
    for (int i = tid; i < N; i += 256) {
        int x = cb[3 * i + 0];
        int y = cb[3 * i + 1];
        int z = cb[3 * i + 2];
        unsigned idx = ((unsigned)x << 12) | ((unsigned)y << 6) | (unsigned)z;
        atomicOr(&bm[idx >> 5], 1u << (idx & 31u));
    }
    __syncthreads();

    // 32 points x 26 neighbors = 832 tests, flat loop (~4/thread)
    for (int i = tid; i < K1_PTS * 26; i += 256) {
        int p = i / 26, k = i % 26;
        int x = cb[3 * (p0 + p) + 0] + NB_OFF[k][0];
        int y = cb[3 * (p0 + p) + 1] + NB_OFF[k][1];
        int z = cb[3 * (p0 + p) + 2] + NB_OFF[k][2];
        out[PRIOR_ELEMS + (size_t)(b * N + p0 + p) * 26 + k] =
            bm_test(bm, x, y, z) ? 1.0f : 0.0f;
    }
}

// ---- K2: pure-streaming prior tiles ----
__global__ void __launch_bounds__(256, 8)
prior_kernel(const float* __restrict__ occ, float* __restrict__ out) {
    const int tid = threadIdx.x;
    const int gp0 = blockIdx.x * PPB2;          // global point index (b*N+p)
    const float inv15 = 1.0f / 15.0f;

    #pragma unroll
    for (int p = 0; p < PPB2; ++p) {
        const float* o = occ + (size_t)(gp0 + p) * 26;
        bool nxm = o[0] != 0.0f, nxp = o[1] != 0.0f;
        bool nym = o[2] != 0.0f, nyp = o[3] != 0.0f;
        bool nzm = o[4] != 0.0f, nzp = o[5] != 0.0f;
        float4* outp = (float4*)(out + (size_t)(gp0 + p) * 4096);
        #pragma unroll
        for (int j = 0; j < 4; ++j) {
            int v4 = j * 256 + tid;             // float4 index in the 4096 tile
            int v = v4 * 4;                     // v = ix*256 + iy*16 + iz
            float gx = (float)((v >> 8) & 15) * inv15;
            float gy = (float)((v >> 4) & 15) * inv15;
            int iz0 = v & 15;
            float m = 1.0f;
            if (!nxm) m = fminf(m, gx);
            if (!nxp) m = fminf(m, 1.0f - gx);
            if (!nym) m = fminf(m, gy);
            if (!nyp) m = fminf(m, 1.0f - gy);
            float r[4];
            #pragma unroll
            for (int k = 0; k < 4; ++k) {
                float gz = (float)(iz0 + k) * inv15;
                float mm = m;
                if (!nzm) mm = fminf(mm, gz);
                if (!nzp) mm = fminf(mm, 1.0f - gz);
                r[k] = mm;
            }
            outp[v4] = make_float4(r[0], r[1], r[2], r[3]);
        }
    }
}

extern "C" void kernel_launch(void* const* d_in, const int* in_sizes, int n_in,
                              void* d_out, int out_size, void* d_ws, size_t ws_size,
                              hipStream_t stream) {
    const int* coords = (const int*)d_in[0];
    float* out = (float*)d_out;
    occ_kernel<<<B * K1_BPB, 256, 0, stream>>>(coords, out);
    prior_kernel<<<B * N / PPB2, 256, 0, stream>>>(out + PRIOR_ELEMS, out);
}